// Round 10
// baseline (1414.519 us; speedup 1.0000x reference)
//
#include <hip/hip_runtime.h>

typedef unsigned int u32;
typedef unsigned long long u64;
typedef _Float16 f16;
typedef _Float16 f16x8 __attribute__((ext_vector_type(8)));
typedef float f32x4 __attribute__((ext_vector_type(4)));

#define DEV __device__ __forceinline__
#define PINA(x) asm volatile("" : "+a"(x))

// ---------------- workspace layout (bytes), ~41.4 MB ----------------
constexpr size_t O_XG0   = 0;                          // [16][512][512] f32 : X@Wih0^T + b0 (p=4j+g cols)
constexpr size_t O_W0HI  = O_XG0   + 16ull*512*512*4;  // [512][128] f16 hi (Whh0, row p=4j+g <-> orig g*128+j)
constexpr size_t O_W0LO  = O_W0HI  + 512ull*128*2;
constexpr size_t O_WIHHI = O_W0LO  + 512ull*128*2;     // [512][128] f16 hi (Wih1 permuted)
constexpr size_t O_WIHLO = O_WIHHI + 512ull*128*2;
constexpr size_t O_WHHHI = O_WIHLO + 512ull*128*2;     // [512][128] f16 hi (Whh1 permuted)
constexpr size_t O_WHHLO = O_WHHHI + 512ull*128*2;
constexpr size_t O_B1P   = O_WHHLO + 512ull*128*2;     // [512] f32 bias1 permuted
constexpr size_t O_MSIG  = O_B1P   + 512*4;            // [1024][1024] f32 mask*sigmoid(adj_w)
constexpr size_t O_ESC   = O_MSIG  + 1024ull*1024*4;   // [16][1024]
constexpr size_t O_EDST  = O_ESC   + 16384*4;
constexpr size_t O_SBUF  = O_EDST  + 16384*4;          // [16][1024] attn-weighted gf
constexpr size_t O_PREPR = O_SBUF  + 16384*4;          // [16][128] price_repr
constexpr size_t O_WFG   = O_PREPR + 2048*4;           // [1024][64] folded Wf graph part
constexpr size_t O_H0HI  = O_WFG   + 65536ull*4;       // [513][16][64] u32 packed f16 col-pairs (hi)
constexpr size_t O_H0LO  = O_H0HI  + 513ull*16*64*4;
constexpr size_t O_P1    = O_H0LO  + 513ull*16*64*4;   // [513][16][512] f32 Wih1@h0+bias1 (p cols)

struct U128 { u64 x, y; };
DEV f16x8 asf16x8(u64 a, u64 b){ U128 t; t.x=a; t.y=b; return __builtin_bit_cast(f16x8, t); }
DEV u32 f16bits(f16 v){ return (u32)__builtin_bit_cast(unsigned short, v); }

DEV float sigm(float x){ x = fminf(fmaxf(x,-30.f),30.f); return __builtin_amdgcn_rcpf(1.f + __expf(-x)); }
DEV float tanh_(float x){ x = fminf(fmaxf(x,-15.f),15.f); float t = __expf(2.f*x); return (t-1.f)*__builtin_amdgcn_rcpf(t+1.f); }

// LDS-only barrier: __syncthreads would drain vmcnt(0) and stall on in-flight
// global prefetch/publish; nothing cross-wave goes through global here.
DEV void bar_lds(){
  asm volatile("s_waitcnt lgkmcnt(0)" ::: "memory");
  __builtin_amdgcn_s_barrier();
  __builtin_amdgcn_sched_barrier(0);
}

// =========================== setup kernel (identical to r7-r9) ===========================
__global__ __launch_bounds__(256) void k_setup(
    const float* __restrict__ price, const float* __restrict__ gf,
    const float* __restrict__ amask, const float* __restrict__ Wih0,
    const float* __restrict__ Whh0, const float* __restrict__ bih0, const float* __restrict__ bhh0,
    const float* __restrict__ Wih1, const float* __restrict__ Whh1,
    const float* __restrict__ bih1, const float* __restrict__ bhh1,
    const float* __restrict__ Wg, const float* __restrict__ a_src, const float* __restrict__ a_dst,
    const float* __restrict__ adj_w, const float* __restrict__ Wf,
    char* __restrict__ ws)
{
  const int tid = threadIdx.x;
  const int jb = blockIdx.x;
  __shared__ float P[16][64];
  __shared__ float Wt[64][128];

  if (jb < 2048) {
    const int tt = jb >> 2, p0 = (jb & 3) * 128;
    float* XG = (float*)(ws + O_XG0);
    { int idx = tid*4; int b = idx>>6, k = idx&63;
      f32x4 v = *(const f32x4*)(price + ((size_t)b*512 + tt)*64 + k);
      *(f32x4*)&P[b][k] = v; }
    { int c = tid>>1, kh = (tid&1)*32;
      int p = p0 + c; int row = (p&3)*128 + (p>>2);
      const float* src = Wih0 + row*64 + kh;
      #pragma unroll
      for (int kk=0; kk<32; kk+=4){ f32x4 v = *(const f32x4*)(src+kk);
        Wt[kh+kk+0][c]=v[0]; Wt[kh+kk+1][c]=v[1]; Wt[kh+kk+2][c]=v[2]; Wt[kh+kk+3][c]=v[3]; } }
    __syncthreads();
    { int c = tid & 127, hh2 = tid >> 7;
      int p = p0 + c; int row = (p&3)*128 + (p>>2);
      float bias = bih0[row] + bhh0[row];
      float acc[8];
      #pragma unroll
      for (int r2=0;r2<8;r2++) acc[r2] = bias;
      for (int k=0;k<64;k++){ float w = Wt[k][c];
        #pragma unroll
        for (int r2=0;r2<8;r2++) acc[r2] += w * P[hh2*8+r2][k]; }
      #pragma unroll
      for (int r2=0;r2<8;r2++)
        XG[((size_t)(hh2*8+r2)*512 + tt)*512 + p0 + c] = acc[r2]; }
  } else if (jb < 3072) {
    int idx = ((jb-2048)<<10) + tid*4;
    float* MS = (float*)(ws + O_MSIG);
    f32x4 m = *(const f32x4*)(amask+idx); f32x4 a = *(const f32x4*)(adj_w+idx);
    f32x4 o;
    #pragma unroll
    for (int e=0;e<4;e++) o[e] = m[e] * (1.f/(1.f+expf(-a[e])));
    *(f32x4*)(MS+idx) = o;
  } else if (jb < 3136) {
    unsigned short* HI = (unsigned short*)(ws+O_W0HI);
    unsigned short* LO = (unsigned short*)(ws+O_W0LO);
    int base = ((jb-3072)*256 + tid)*4;
    #pragma unroll
    for (int e=0;e<4;e++){ int idx = base+e; int p = idx>>7, k = idx&127;
      int row = (p&3)*128 + (p>>2);
      float w = Whh0[row*128 + k];
      f16 hi = (f16)w; f16 lo = (f16)((w - (float)hi)*4096.f);
      HI[idx] = (unsigned short)f16bits(hi); LO[idx] = (unsigned short)f16bits(lo); }
  } else if (jb < 3200) {
    unsigned short* HI = (unsigned short*)(ws+O_WIHHI);
    unsigned short* LO = (unsigned short*)(ws+O_WIHLO);
    int base = ((jb-3136)*256 + tid)*4;
    #pragma unroll
    for (int e=0;e<4;e++){ int idx = base+e; int p = idx>>7, k = idx&127;
      int row = (p&3)*128 + (p>>2);
      float w = Wih1[row*128 + k];
      f16 hi = (f16)w; f16 lo = (f16)((w - (float)hi)*4096.f);
      HI[idx] = (unsigned short)f16bits(hi); LO[idx] = (unsigned short)f16bits(lo); }
  } else if (jb < 3264) {
    unsigned short* HI = (unsigned short*)(ws+O_WHHHI);
    unsigned short* LO = (unsigned short*)(ws+O_WHHLO);
    int base = ((jb-3200)*256 + tid)*4;
    #pragma unroll
    for (int e=0;e<4;e++){ int idx = base+e; int p = idx>>7, k = idx&127;
      int row = (p&3)*128 + (p>>2);
      float w = Whh1[row*128 + k];
      f16 hi = (f16)w; f16 lo = (f16)((w - (float)hi)*4096.f);
      HI[idx] = (unsigned short)f16bits(hi); LO[idx] = (unsigned short)f16bits(lo); }
  } else if (jb < 3265) {
    float* B1 = (float*)(ws+O_B1P);
    for (int p = tid; p < 512; p += 256){ int row = (p&3)*128 + (p>>2); B1[p] = bih1[row]+bhh1[row]; }
  } else if (jb < 3281) {
    float cs = 0.f, cd = 0.f;
    for (int g=0; g<64; g++){ cs += Wg[g]*a_src[g]; cd += Wg[g]*a_dst[g]; }
    float* ESC = (float*)(ws+O_ESC); float* EDS = (float*)(ws+O_EDST);
    int base = (jb-3265)*1024 + tid*4;
    f32x4 g4 = *(const f32x4*)(gf+base);
    f32x4 e1, e2;
    #pragma unroll
    for (int e=0;e<4;e++){ e1[e] = g4[e]*cs; e2[e] = g4[e]*cd; }
    *(f32x4*)(ESC+base) = e1; *(f32x4*)(EDS+base) = e2;
  } else {
    float* WFG = (float*)(ws+O_WFG);
    int n = (jb-3281)*4 + (tid>>6); int f = tid & 63;
    float acc = 0.f;
    for (int g=0; g<64; g++) acc += Wg[g] * Wf[((size_t)(128 + n*64 + g))*64 + f];
    WFG[n*64 + f] = acc;
  }
}

// =========================== LDS for recurrence ===========================
// hbuf in LANE-READ ORDER: 16B chunk for (ks, lane) at byte (ks*64+lane)*16, so the
// A-read is lane i -> base + i*16 = the m134 conflict-free b128 pattern.
// Element (A-row m, f16-col k) lives at u32 idx (k>>5)*256 + ((k>>3)&3)*64 + m*4 + ((k>>1)&3).
// (r9's stride-68 row layout was an 8-way conflict: bank 4(r+q) mod 32 -> 786K conflict cycles.)
struct SM3 { u32 hbuf[2][1024]; };

// =========================== recurrence CU (sequential phases, no flags) ===========================
// 2 blocks x 512 thr; wave w owns h-cols [16w,16w+16); tile t = gate t (B row p=4j+t).
// A rows interleave hi/lo per batch so the hi/lo combine is lane-local (no shuffles).
template<int LAYER>
DEV void rnn3(char* __restrict__ ws, int bg, int tid, SM3* sm)
{
  const int lane = tid & 63, w = tid >> 6;
  const int r = lane & 15, q = lane >> 4;
  const int j = w*16 + r;                 // h-col owned in epilogue
  const int b0 = bg*8 + 2*q;              // epilogue batches: b0, b0+1

  const u64* WHI = (const u64*)(ws + (LAYER ? O_WHHHI : O_W0HI));
  const u64* WLO = (const u64*)(ws + (LAYER ? O_WHHLO : O_W0LO));
  f16x8 Bhi[4][4], Blo[4][4];
  #pragma unroll
  for (int t=0;t<4;t++)
    #pragma unroll
    for (int ks=0;ks<4;ks++){
      int o = (4*j + t)*32 + ks*8 + q*2;   // W' row p=4j+t, k-slice q*8 within ks*32
      Bhi[t][ks] = asf16x8(WHI[o], WHI[o+1]);
      Blo[t][ks] = asf16x8(WLO[o], WLO[o+1]);
    }
  #pragma unroll
  for (int t=0;t<4;t++)
    #pragma unroll
    for (int ks=0;ks<4;ks++){ PINA(Bhi[t][ks]); PINA(Blo[t][ks]); }

  u32* H0HIp = (u32*)(ws+O_H0HI);
  u32* H0LOp = (u32*)(ws+O_H0LO);
  const float* P1f = (const float*)(ws+O_P1);
  const float* XG  = (const float*)(ws+O_XG0);

  for (int idx = tid; idx < 2*1024; idx += 512) ((u32*)sm->hbuf)[idx] = 0u;

  // ---- 2-ahead pipeline of the per-step additive term (XG for L0, P1 for L1) ----
  f32x4 ac[2], aN[2], aNN[2];
  #pragma unroll
  for (int d=0; d<2; ++d){
    if constexpr (!LAYER) {
      ac[d] = *(const f32x4*)(XG + ((size_t)((b0+d)*512 + 0))*512 + 4*j);
      aN[d] = *(const f32x4*)(XG + ((size_t)((b0+d)*512 + 1))*512 + 4*j);
    } else {
      ac[d] = *(const f32x4*)(P1f + ((size_t)(1*16 + b0+d))*512 + 4*j);
      aN[d] = *(const f32x4*)(P1f + ((size_t)(2*16 + b0+d))*512 + 4*j);
    }
    aNN[d] = ac[d];
  }
  float cst[2] = {0.f, 0.f};
  int cur = 0;
  __syncthreads();

  for (int s=1; s<=512; ++s){
    // ---- prefetch additive term for s+2 (dummy reload at tail, unused) ----
    { int sp = (s<=510) ? (s+2) : 512;
      #pragma unroll
      for (int d=0; d<2; ++d){
        if constexpr (!LAYER)
          aNN[d] = *(const f32x4*)(XG + ((size_t)((b0+d)*512 + sp-1))*512 + 4*j);
        else
          aNN[d] = *(const f32x4*)(P1f + ((size_t)(sp*16 + b0+d))*512 + 4*j);
      } }

    // ---- MFMA: 32/wave. accA = A x Whi, accB = A x Wlo. A-read conflict-free ----
    f32x4 accA[4], accB[4];
    #pragma unroll
    for (int t=0;t<4;t++){ accA[t]=f32x4{0,0,0,0}; accB[t]=f32x4{0,0,0,0}; }
    #pragma unroll
    for (int ks=0;ks<4;ks++){
      f16x8 av = *(const f16x8*)&sm->hbuf[cur][ks*256 + lane*4];
      #pragma unroll
      for (int t=0;t<4;t++){
        accA[t] = __builtin_amdgcn_mfma_f32_16x16x32_f16(av, Bhi[t][ks], accA[t], 0,0,0);
        accB[t] = __builtin_amdgcn_mfma_f32_16x16x32_f16(av, Blo[t][ks], accB[t], 0,0,0);
      }
    }

    // ---- lane-local combine + epilogue: D row 4q+i -> i=0:hi(b0) 1:lo(b0) 2:hi(b1) 3:lo(b1) ----
    float hv[2];
    #pragma unroll
    for (int d=0; d<2; ++d){
      float g0 = accA[0][2*d] + (accA[0][2*d+1] + accB[0][2*d])*(1.f/4096.f);
      float g1 = accA[1][2*d] + (accA[1][2*d+1] + accB[1][2*d])*(1.f/4096.f);
      float g2 = accA[2][2*d] + (accA[2][2*d+1] + accB[2][2*d])*(1.f/4096.f);
      float g3 = accA[3][2*d] + (accA[3][2*d+1] + accB[3][2*d])*(1.f/4096.f);
      float I = sigm(g0 + ac[d][0]);
      float F = sigm(g1 + ac[d][1]);
      float G = tanh_(g2 + ac[d][2]);
      float O = sigm(g3 + ac[d][3]);
      cst[d] = F*cst[d] + I*G;
      hv[d] = O * tanh_(cst[d]);
    }

    // ---- pack f16 hi/lo col-pairs (shfl over adjacent r), write LDS + publish ----
    u32 hp[2], lp[2];
    #pragma unroll
    for (int d=0; d<2; ++d){
      f16 hh = (f16)hv[d]; f16 hl = (f16)((hv[d] - (float)hh)*4096.f);
      u32 hb = f16bits(hh), lb = f16bits(hl);
      u32 oh = (u32)__shfl_xor((int)hb, 1, 64);
      u32 ol = (u32)__shfl_xor((int)lb, 1, 64);
      hp[d] = hb | (oh<<16); lp[d] = lb | (ol<<16);
    }
    int nxt = cur^1;
    if ((r & 1) == 0){
      const int cp = w*8 + (r>>1);                       // packed col-pair index
      const int wbase = (cp>>4)*256 + ((cp>>2)&3)*64 + 16*q + (cp&3);
      u32* hb8 = sm->hbuf[nxt];
      hb8[wbase+ 0] = hp[0];    // row 4q   : hi(b0)
      hb8[wbase+ 4] = lp[0];    // row 4q+1 : lo(b0)
      hb8[wbase+ 8] = hp[1];    // row 4q+2 : hi(b1)
      hb8[wbase+12] = lp[1];    // row 4q+3 : lo(b1)
      if constexpr (!LAYER){
        const int cpo = cp;
        H0HIp[(s*16 + b0  )*64 + cpo] = hp[0];
        H0LOp[(s*16 + b0  )*64 + cpo] = lp[0];
        H0HIp[(s*16 + b0+1)*64 + cpo] = hp[1];
        H0LOp[(s*16 + b0+1)*64 + cpo] = lp[1];
      }
    }
    if constexpr (LAYER){
      if (s == 512){
        ((float*)(ws+O_PREPR))[(b0  )*128 + j] = hv[0];
        ((float*)(ws+O_PREPR))[(b0+1)*128 + j] = hv[1];
      }
    }

    bar_lds();   // LDS-only: publish stores + prefetch loads stay in flight

    cur = nxt;
    #pragma unroll
    for (int d=0; d<2; ++d){ ac[d] = aN[d]; aN[d] = aNN[d]; }
  }
}

__global__
__attribute__((amdgpu_flat_work_group_size(512,512), amdgpu_waves_per_eu(2,2)))
void k_lstm0(char* __restrict__ ws)
{
  __shared__ SM3 sm;
  rnn3<0>(ws, blockIdx.x, threadIdx.x, &sm);
}

__global__
__attribute__((amdgpu_flat_work_group_size(512,512), amdgpu_waves_per_eu(2,2)))
void k_lstm1(char* __restrict__ ws)
{
  __shared__ SM3 sm;
  rnn3<1>(ws, blockIdx.x, threadIdx.x, &sm);
}

// =========================== P1[s] = Wih1 @ h0(s) + bias1, one block per s ===========================
__global__ __launch_bounds__(512) void k_gemm1(char* __restrict__ ws)
{
  const int tid = threadIdx.x;
  const int lane = tid & 63, w = tid >> 6;
  const int c = lane & 15, q = lane >> 4;
  const int s = blockIdx.x + 1;   // 1..512

  const u64* WHI = (const u64*)(ws+O_WIHHI);
  const u64* WLO = (const u64*)(ws+O_WIHLO);
  f16x8 Bhi[4][4], Blo[4][4];
  #pragma unroll
  for (int t=0;t<4;t++)
    #pragma unroll
    for (int ks=0;ks<4;ks++){
      int o = (w*64 + t*16 + c)*32 + ks*8 + q*2;
      Bhi[t][ks] = asf16x8(WHI[o], WHI[o+1]);
      Blo[t][ks] = asf16x8(WLO[o], WLO[o+1]);
    }
  float bias_t[4];
  #pragma unroll
  for (int t=0;t<4;t++) bias_t[t] = ((const float*)(ws+O_B1P))[w*64 + t*16 + c];

  const u64* H0HIu = (const u64*)(ws+O_H0HI);
  const u64* H0LOu = (const u64*)(ws+O_H0LO);
  float* P1f = (float*)(ws+O_P1);

  u64 AH[4][2], AL[4][2];
  #pragma unroll
  for (int ks=0;ks<4;ks++){
    size_t o = ((size_t)(s*16 + c))*32 + ks*8 + q*2;   // A row = batch = lane&15
    AH[ks][0]=H0HIu[o]; AH[ks][1]=H0HIu[o+1];
    AL[ks][0]=H0LOu[o]; AL[ks][1]=H0LOu[o+1];
  }
  f32x4 acc[4], accl[4];
  #pragma unroll
  for (int t=0;t<4;t++){ acc[t]=f32x4{0,0,0,0}; accl[t]=f32x4{0,0,0,0}; }
  #pragma unroll
  for (int ks=0;ks<4;ks++){
    f16x8 ah  = asf16x8(AH[ks][0], AH[ks][1]);
    f16x8 al_ = asf16x8(AL[ks][0], AL[ks][1]);
    #pragma unroll
    for (int t=0;t<4;t++){
      acc[t]  = __builtin_amdgcn_mfma_f32_16x16x32_f16(ah,  Bhi[t][ks], acc[t],  0,0,0);
      accl[t] = __builtin_amdgcn_mfma_f32_16x16x32_f16(ah,  Blo[t][ks], accl[t], 0,0,0);
      accl[t] = __builtin_amdgcn_mfma_f32_16x16x32_f16(al_, Bhi[t][ks], accl[t], 0,0,0);
    }
  }
  #pragma unroll
  for (int t=0;t<4;t++){
    #pragma unroll
    for (int i=0;i<4;i++){
      float v = acc[t][i] + accl[t][i]*(1.f/4096.f) + bias_t[t];
      P1f[((size_t)(s*16 + q*4 + i))*512 + w*64 + t*16 + c] = v;
    }
  }
}

// =========================== attention ===========================
DEV float wredMax(float v){
  #pragma unroll
  for (int o=32;o;o>>=1) v = fmaxf(v, __shfl_xor(v,o,64));
  return v;
}
DEV float wredSum(float v){
  #pragma unroll
  for (int o=32;o;o>>=1) v += __shfl_xor(v,o,64);
  return v;
}

__global__ __launch_bounds__(512) void k_attn(const float* __restrict__ gf,
                                              char* __restrict__ ws, float* __restrict__ out)
{
  __shared__ float red[8];
  const int tid = threadIdx.x;
  const int row = blockIdx.x;
  const int b = row >> 10, i = row & 1023;
  const int w = tid >> 6;
  const float* MSIG = (const float*)(ws+O_MSIG);
  const float* ESC  = (const float*)(ws+O_ESC);
  const float* EDST = (const float*)(ws+O_EDST);
  float* SBUF = (float*)(ws+O_SBUF);

  const float ei = ESC[(b<<10)+i];
  float pv[2];
  float mx = -3.4e38f;
  #pragma unroll
  for (int k2=0;k2<2;k2++){
    int jj = tid + (k2<<9);
    float sc = (ei + EDST[(b<<10)+jj]) * MSIG[((size_t)i<<10)+jj];
    pv[k2] = sc; mx = fmaxf(mx, sc);
  }
  mx = wredMax(mx);
  if ((tid&63)==0) red[w] = mx;
  __syncthreads();
  mx = fmaxf(fmaxf(fmaxf(red[0],red[1]),fmaxf(red[2],red[3])),
             fmaxf(fmaxf(red[4],red[5]),fmaxf(red[6],red[7])));
  __syncthreads();

  float sum = 0.f;
  #pragma unroll
  for (int k2=0;k2<2;k2++){ pv[k2] = __expf(pv[k2]-mx); sum += pv[k2]; }
  sum = wredSum(sum);
  if ((tid&63)==0) red[w] = sum;
  __syncthreads();
  sum = red[0]+red[1]+red[2]+red[3]+red[4]+red[5]+red[6]+red[7];
  __syncthreads();

  const float rinv = 1.0f / sum;
  float sacc = 0.f;
  const size_t obase = 16 + ((size_t)row << 10);
  #pragma unroll
  for (int k2=0;k2<2;k2++){
    int jj = tid + (k2<<9);
    float a = pv[k2]*rinv;
    out[obase + jj] = a;
    sacc += a * gf[(b<<10)+jj];
  }
  sacc = wredSum(sacc);
  if ((tid&63)==0) red[w] = sacc;
  __syncthreads();
  if (tid==0) SBUF[row] = red[0]+red[1]+red[2]+red[3]+red[4]+red[5]+red[6]+red[7];
}

// =========================== final MLP ===========================
__global__ __launch_bounds__(256) void k_mlp(const float* __restrict__ Wf, const float* __restrict__ bf,
  const float* __restrict__ W1, const float* __restrict__ b1,
  const float* __restrict__ W2, const float* __restrict__ b2,
  const char* __restrict__ ws, float* __restrict__ out)
{
  __shared__ float sS[1024];
  __shared__ float sP[128];
  __shared__ float sR[256];
  __shared__ float sF[96];
  const int b = blockIdx.x, tid = threadIdx.x;
  const float* SBUF = (const float*)(ws+O_SBUF);
  const float* PREPR= (const float*)(ws+O_PREPR);
  const float* WFG  = (const float*)(ws+O_WFG);

  { f32x4 v = *(const f32x4*)(SBUF + (b<<10) + tid*4); *(f32x4*)&sS[tid*4] = v; }
  if (tid < 128) sP[tid] = PREPR[b*128 + tid];
  __syncthreads();

  const int f = tid & 63, kq = tid >> 6;
  float acc = 0.f;
  for (int n = kq*256; n < kq*256+256; ++n) acc += sS[n] * WFG[n*64 + f];
  if (kq == 0) {
    for (int k=0;k<128;k++) acc += sP[k] * Wf[k*64 + f];
    acc += bf[f];
  }
  sR[tid] = acc; __syncthreads();
  if (tid < 64) {
    float v = sR[tid] + sR[tid+64] + sR[tid+128] + sR[tid+192];
    sF[tid] = fmaxf(v, 0.f);
  }
  __syncthreads();
  if (tid < 32) {
    float a = 0.f;
    for (int k=0;k<64;k++) a += sF[k] * W1[k*32 + tid];
    sF[64+tid] = fmaxf(a + b1[tid], 0.f);
  }
  __syncthreads();
  if (tid == 0) {
    float a = 0.f;
    for (int k=0;k<32;k++) a += sF[64+k] * W2[k];
    out[b] = a + b2[0];
  }
}

// =========================== launch ===========================
extern "C" void kernel_launch(void* const* d_in, const int* in_sizes, int n_in,
                              void* d_out, int out_size, void* d_ws, size_t ws_size,
                              hipStream_t stream)
{
  const float* price = (const float*)d_in[0];
  const float* gf    = (const float*)d_in[1];
  const float* amask = (const float*)d_in[2];
  const float* Wih0  = (const float*)d_in[3];
  const float* Whh0  = (const float*)d_in[4];
  const float* bih0  = (const float*)d_in[5];
  const float* bhh0  = (const float*)d_in[6];
  const float* Wih1  = (const float*)d_in[7];
  const float* Whh1  = (const float*)d_in[8];
  const float* bih1  = (const float*)d_in[9];
  const float* bhh1  = (const float*)d_in[10];
  const float* Wg    = (const float*)d_in[11];
  const float* asrc  = (const float*)d_in[12];
  const float* adst  = (const float*)d_in[13];
  const float* adjw  = (const float*)d_in[14];
  const float* Wf    = (const float*)d_in[15];
  const float* bf    = (const float*)d_in[16];
  const float* W1    = (const float*)d_in[17];
  const float* b1    = (const float*)d_in[18];
  const float* W2    = (const float*)d_in[19];
  const float* b2    = (const float*)d_in[20];
  char* ws = (char*)d_ws;
  float* out = (float*)d_out;

  k_setup<<<dim3(3537), dim3(256), 0, stream>>>(price, gf, amask, Wih0, Whh0, bih0, bhh0,
                                                Wih1, Whh1, bih1, bhh1, Wg, asrc, adst, adjw, Wf, ws);
  k_attn<<<dim3(16384), dim3(512), 0, stream>>>(gf, ws, out);
  k_lstm0<<<dim3(2), dim3(512), 0, stream>>>(ws);
  k_gemm1<<<dim3(512), dim3(512), 0, stream>>>(ws);
  k_lstm1<<<dim3(2), dim3(512), 0, stream>>>(ws);
  k_mlp<<<dim3(16), dim3(256), 0, stream>>>(Wf, bf, W1, b1, W2, b2, (const char*)ws, out);
}